// Round 1
// baseline (702.540 us; speedup 1.0000x reference)
//
#include <hip/hip_runtime.h>

#define B_   16
#define CIN  256
#define T_   8192
#define D_   64
#define KK   512

// ---------------------------------------------------------------------------
// Kernel 0: n2[k] = ||codebook[k]||^2
// ---------------------------------------------------------------------------
__global__ void n2_kernel(const float* __restrict__ cb, float* __restrict__ n2) {
    int k = blockIdx.x * blockDim.x + threadIdx.x;
    if (k < KK) {
        const float* ek = cb + (size_t)k * D_;
        float s0 = 0.f, s1 = 0.f, s2 = 0.f, s3 = 0.f;
        #pragma unroll
        for (int q = 0; q < 16; ++q) {
            float4 v = *(const float4*)(ek + (q << 2));
            s0 = fmaf(v.x, v.x, s0);
            s1 = fmaf(v.y, v.y, s1);
            s2 = fmaf(v.z, v.z, s2);
            s3 = fmaf(v.w, v.w, s3);
        }
        n2[k] = (s0 + s1) + (s2 + s3);
    }
}

// ---------------------------------------------------------------------------
// Kernel 1: z[b*T+t][d] = sum_c x[b][c][t] * W[d][c] + bias[d]
// 256 blocks (one per 512-t slab), 512 threads, 8t x 8d register tile.
// W transposed in LDS (pad 68 to break bank conflicts); x chunks (16 c-rows)
// double-buffered, loads issued two chunks ahead.
// ---------------------------------------------------------------------------
__global__ __launch_bounds__(512, 2) void zproj_kernel(
    const float* __restrict__ x, const float* __restrict__ W,
    const float* __restrict__ bias, float* __restrict__ z)
{
    __shared__ float Wt[CIN][68];        // 68 KB, Wt[c][d]
    __shared__ float xs[2][16][512];     // 64 KB, xs[buf][c][t]

    const int tid = threadIdx.x;
    const int bid = blockIdx.x;
    const int b   = bid >> 4;
    const int t0  = (bid & 15) << 9;     // *512

    // stage W transposed: W[d*256+c] -> Wt[c][d]
    for (int i = tid; i < CIN * D_; i += 512) {
        int d = i >> 8, c = i & 255;
        Wt[c][d] = W[i];
    }

    const int dg = (tid & 7) << 3;       // d base (0..56)
    const int tg = (tid >> 3) << 3;      // t base within slab (0..504)

    float bv[8];
    #pragma unroll
    for (int j = 0; j < 8; ++j) bv[j] = bias[dg + j];

    float acc[8][8];
    #pragma unroll
    for (int i = 0; i < 8; ++i)
        #pragma unroll
        for (int j = 0; j < 8; ++j) acc[i][j] = 0.f;

    const float* xb = x + ((size_t)b * CIN) * T_ + t0;

#define LOADX(dst, ch) do {                                                   \
        const float* xc_ = xb + (size_t)(ch) * 16 * T_;                       \
        _Pragma("unroll")                                                     \
        for (int p = 0; p < 4; ++p) {                                         \
            int j_ = tid + (p << 9);                                          \
            dst[p] = *(const float4*)(xc_ + (size_t)(j_ >> 7) * T_            \
                                      + ((j_ & 127) << 2));                   \
        }                                                                     \
    } while (0)

#define WRITEX(src, bsel) do {                                                \
        _Pragma("unroll")                                                     \
        for (int p = 0; p < 4; ++p) {                                         \
            int j_ = tid + (p << 9);                                          \
            *(float4*)(&xs[bsel][j_ >> 7][(j_ & 127) << 2]) = src[p];         \
        }                                                                     \
    } while (0)

#define COMPUTE(bsel, ch) do {                                                \
        const int cb0_ = (ch) << 4;                                           \
        _Pragma("unroll")                                                     \
        for (int cc = 0; cc < 16; ++cc) {                                     \
            float4 w0 = *(const float4*)(&Wt[cb0_ + cc][dg]);                 \
            float4 w1 = *(const float4*)(&Wt[cb0_ + cc][dg + 4]);             \
            float4 x0 = *(const float4*)(&xs[bsel][cc][tg]);                  \
            float4 x1 = *(const float4*)(&xs[bsel][cc][tg + 4]);              \
            float wv[8] = {w0.x, w0.y, w0.z, w0.w, w1.x, w1.y, w1.z, w1.w};   \
            float xv[8] = {x0.x, x0.y, x0.z, x0.w, x1.x, x1.y, x1.z, x1.w};   \
            _Pragma("unroll")                                                 \
            for (int i = 0; i < 8; ++i)                                       \
                _Pragma("unroll")                                             \
                for (int j2 = 0; j2 < 8; ++j2)                                \
                    acc[i][j2] = fmaf(xv[i], wv[j2], acc[i][j2]);             \
        }                                                                     \
    } while (0)

    float4 stA[4], stB[4];
    LOADX(stA, 0);
    WRITEX(stA, 0);
    LOADX(stB, 1);
    __syncthreads();

    #pragma unroll 1
    for (int ch = 0; ch < 16; ch += 2) {
        WRITEX(stB, 1);                       // chunk ch+1 -> buf1
        if (ch + 2 < 16) LOADX(stA, ch + 2);  // issue chunk ch+2
        COMPUTE(0, ch);
        __syncthreads();
        if (ch + 2 < 16) WRITEX(stA, 0);      // chunk ch+2 -> buf0
        if (ch + 3 < 16) LOADX(stB, ch + 3);  // issue chunk ch+3
        COMPUTE(1, ch + 1);
        __syncthreads();
    }

    // epilogue: bias + store z rows
    float* zr = z + ((size_t)(b * T_ + t0 + tg)) * D_ + dg;
    #pragma unroll
    for (int i = 0; i < 8; ++i) {
        float4 o0, o1;
        o0.x = acc[i][0] + bv[0]; o0.y = acc[i][1] + bv[1];
        o0.z = acc[i][2] + bv[2]; o0.w = acc[i][3] + bv[3];
        o1.x = acc[i][4] + bv[4]; o1.y = acc[i][5] + bv[5];
        o1.z = acc[i][6] + bv[6]; o1.w = acc[i][7] + bv[7];
        *(float4*)(zr + (size_t)i * D_)     = o0;
        *(float4*)(zr + (size_t)i * D_ + 4) = o1;
    }
#undef LOADX
#undef WRITEX
#undef COMPUTE
}

// ---------------------------------------------------------------------------
// Kernel 2: per t, n = ||z||^2 + min_k( n2[k] - 2 z.e_k ); out[t][0..1] = n
// Codebook rows accessed uniformly (k is a uniform loop var) -> scalar loads.
// ---------------------------------------------------------------------------
__global__ __launch_bounds__(256, 2) void vq_kernel(
    const float* __restrict__ z, const float* __restrict__ cb,
    const float* __restrict__ n2, float* __restrict__ out)
{
    const int t = blockIdx.x * 256 + threadIdx.x;
    const float* zr = z + (size_t)t * D_;

    float zv[64];
    #pragma unroll
    for (int p = 0; p < 16; ++p) {
        float4 v = *(const float4*)(zr + (p << 2));
        zv[p * 4 + 0] = v.x; zv[p * 4 + 1] = v.y;
        zv[p * 4 + 2] = v.z; zv[p * 4 + 3] = v.w;
    }

    float zn = 0.f;
    #pragma unroll
    for (int d = 0; d < 64; ++d) zn = fmaf(zv[d], zv[d], zn);

    float best = 3.0e38f;
    #pragma unroll 2
    for (int k = 0; k < KK; ++k) {
        const float* ek = cb + ((size_t)k << 6);   // uniform address
        float d0 = 0.f, d1 = 0.f, d2 = 0.f, d3 = 0.f;
        #pragma unroll
        for (int q = 0; q < 16; ++q) {
            d0 = fmaf(zv[4 * q + 0], ek[4 * q + 0], d0);
            d1 = fmaf(zv[4 * q + 1], ek[4 * q + 1], d1);
            d2 = fmaf(zv[4 * q + 2], ek[4 * q + 2], d2);
            d3 = fmaf(zv[4 * q + 3], ek[4 * q + 3], d3);
        }
        float s = fmaf(-2.f, (d0 + d1) + (d2 + d3), n2[k]);
        best = fminf(best, s);
    }

    float n = zn + best;
    float2 o; o.x = n; o.y = n;
    *(float2*)(out + (size_t)t * 2) = o;
}

// ---------------------------------------------------------------------------
extern "C" void kernel_launch(void* const* d_in, const int* in_sizes, int n_in,
                              void* d_out, int out_size, void* d_ws, size_t ws_size,
                              hipStream_t stream) {
    const float* x    = (const float*)d_in[0];
    const float* W    = (const float*)d_in[1];
    const float* bias = (const float*)d_in[2];
    const float* cb   = (const float*)d_in[3];
    float* out = (float*)d_out;

    float* z  = (float*)d_ws;                       // B*T*D floats = 33.5 MB
    float* n2 = z + (size_t)B_ * T_ * D_;           // 512 floats

    n2_kernel<<<2, 256, 0, stream>>>(cb, n2);
    zproj_kernel<<<256, 512, 0, stream>>>(x, W, bias, z);
    vq_kernel<<<(B_ * T_) / 256, 256, 0, stream>>>(z, cb, n2, out);
}